// Round 1
// baseline (209.715 us; speedup 1.0000x reference)
//
#include <hip/hip_runtime.h>
#include <hip/hip_bf16.h>

// Problem constants (from reference)
#define N_NODES 4096
#define IN_DIM  512
#define HID_DIM 256
#define OUT_DIM 64
#define PROP_STEP 10
#define MAX_DEG 128            // mean degree ~41; padded to multiple of 16
#define GEMM_BLOCKS 256        // fused full-K MLP blocks (16 rows each)
#define LAM_CONST (1.0f/0.9f - 1.0f)
#define SCAD_A 3.7f

__device__ __forceinline__ ushort f2bf(float f) {
    unsigned u = __float_as_uint(f);
    unsigned r = (u + 0x7FFFu + ((u >> 16) & 1u)) >> 16;  // RNE
    return (ushort)r;
}
__device__ __forceinline__ unsigned pack2(float lo, float hi) {
    return (unsigned)f2bf(lo) | ((unsigned)f2bf(hi) << 16);
}
__device__ __forceinline__ float bflo(unsigned u) { return __uint_as_float(u << 16); }
__device__ __forceinline__ float bfhi(unsigned u) { return __uint_as_float(u & 0xFFFF0000u); }

// ---------------------------------------------------------------------------
// Fused build kernel: blocks [0, 256) each compute the FULL MLP for 16 rows:
// h = relu(F@W1 + b1) (K=512 staged in 16-wide LDS chunks), then
// F0 = h@W2 + b2 with W2 staged in 64-wide chunks REUSING the same LDS
// buffer. Blocks [256, 256+4096) build one ELL adjacency row each from dense
// fp32 A. This removes the old split-K Hp intermediate (32 MB round-trip)
// AND the separate mlp2r dispatch (one ~10-13 us kernel boundary).
// NOTE (measured, prior session R8+R12): in-kernel grid-wide sync costs
// 55-85 us/sync on MI355X; a kernel boundary does the same visibility work
// in ~10 us. Hence per-step dispatches for propagation remain optimal.
// ---------------------------------------------------------------------------
__global__ __launch_bounds__(512) void build_all(
    const float* __restrict__ A, const float* __restrict__ F,
    const float* __restrict__ W1, const float* __restrict__ b1,
    const float* __restrict__ W2, const float* __restrict__ b2,
    float* __restrict__ F0,
    int* __restrict__ ell, int* __restrict__ deg,
    float* __restrict__ invD, float* __restrict__ invDsq)
{
    if (blockIdx.x < GEMM_BLOCKS) {
        __shared__ float sFt[16][20];     // [k][row], 1.25 KB
        __shared__ float sW[16][272];     // W1 chunk; reused as [64][68] for W2
        __shared__ float sH[16][260];     // relu hidden, 16.25 KB
        int t  = threadIdx.x;
        int m0 = blockIdx.x * 16;
        // phase-1 compute mapping: 2 rows x 4 cols per thread
        int tm = (t & 7) * 2;             // row 0..14 (pairs)
        int tn = (t >> 3) * 4;            // col 0..252
        int fr = t >> 4, fk = t & 15;     // F staging (t < 256)
        int wr = t >> 6, wc = (t & 63) * 4; // W1 staging
        float a00 = 0.f, a01 = 0.f, a02 = 0.f, a03 = 0.f;
        float a10 = 0.f, a11 = 0.f, a12 = 0.f, a13 = 0.f;
        for (int kc = 0; kc < IN_DIM; kc += 16) {
            float fv = 0.0f;
            if (t < 256) fv = F[(size_t)(m0 + fr) * IN_DIM + kc + fk];
            float4 w0 = *(const float4*)(W1 + (size_t)(kc + wr)     * HID_DIM + wc);
            float4 w1 = *(const float4*)(W1 + (size_t)(kc + 8 + wr) * HID_DIM + wc);
            __syncthreads();
            if (t < 256) sFt[fk][fr] = fv;
            *(float4*)&sW[wr][wc]     = w0;
            *(float4*)&sW[8 + wr][wc] = w1;
            __syncthreads();
#pragma unroll
            for (int k = 0; k < 16; k++) {
                float2 a = *(const float2*)&sFt[k][tm];
                float4 b = *(const float4*)&sW[k][tn];
                a00 += a.x * b.x; a01 += a.x * b.y; a02 += a.x * b.z; a03 += a.x * b.w;
                a10 += a.y * b.x; a11 += a.y * b.y; a12 += a.y * b.z; a13 += a.y * b.w;
            }
        }
        float4 bb = *(const float4*)(b1 + tn);
        *(float4*)&sH[tm][tn] = make_float4(
            fmaxf(a00 + bb.x, 0.f), fmaxf(a01 + bb.y, 0.f),
            fmaxf(a02 + bb.z, 0.f), fmaxf(a03 + bb.w, 0.f));
        *(float4*)&sH[tm + 1][tn] = make_float4(
            fmaxf(a10 + bb.x, 0.f), fmaxf(a11 + bb.y, 0.f),
            fmaxf(a12 + bb.z, 0.f), fmaxf(a13 + bb.w, 0.f));
        __syncthreads();
        // phase 2: F0[16][64] = sH @ W2 + b2, W2 staged in 64-k chunks in sW
        int r2 = t >> 5;                  // 0..15
        int c2 = (t & 31) * 2;            // 0..62
        float accA = b2[c2], accB = b2[c2 + 1];
        float (*sW2c)[68] = (float(*)[68])sW;
        for (int kc = 0; kc < HID_DIM; kc += 64) {
            __syncthreads();              // protect previous chunk readers
            for (int i = t; i < 1024; i += 512) {
                int kk = i >> 4, cc = (i & 15) * 4;
                *(float4*)&sW2c[kk][cc] =
                    *(const float4*)(W2 + (size_t)(kc + kk) * OUT_DIM + cc);
            }
            __syncthreads();
#pragma unroll 8
            for (int k = 0; k < 64; k++) {
                float  hb = sH[r2][kc + k];
                float2 w2 = *(const float2*)&sW2c[k][c2];
                accA += hb * w2.x; accB += hb * w2.y;
            }
        }
        *(float2*)(F0 + (size_t)(m0 + r2) * OUT_DIM + c2) = make_float2(accA, accB);
    } else {
        __shared__ int cnt;
        int i = blockIdx.x - GEMM_BLOCKS;
        int t = threadIdx.x;
        if (t == 0) cnt = 0;
        __syncthreads();
        const float4* row = (const float4*)(A + (size_t)i * N_NODES);
        for (int q = t; q < N_NODES / 4; q += 512) {
            float4 v = row[q];
            if (v.x != 0.0f) { int p = atomicAdd(&cnt, 1); if (p < MAX_DEG) ell[i * MAX_DEG + p] = q * 4 + 0; }
            if (v.y != 0.0f) { int p = atomicAdd(&cnt, 1); if (p < MAX_DEG) ell[i * MAX_DEG + p] = q * 4 + 1; }
            if (v.z != 0.0f) { int p = atomicAdd(&cnt, 1); if (p < MAX_DEG) ell[i * MAX_DEG + p] = q * 4 + 2; }
            if (v.w != 0.0f) { int p = atomicAdd(&cnt, 1); if (p < MAX_DEG) ell[i * MAX_DEG + p] = q * 4 + 3; }
        }
        __syncthreads();
        if (t == 0) {
            int c = cnt;
            if (c > MAX_DEG) c = MAX_DEG;
            deg[i] = c;
            int pad = (c + 15) & ~15;
            if (pad > MAX_DEG) pad = MAX_DEG;
            for (int p = c; p < pad; p++) ell[i * MAX_DEG + p] = i;  // self pad, masked later
            float d = (float)(cnt + 1);   // true degree + self loop
            invD[i] = 1.0f / d;
            invDsq[i] = rsqrtf(d);
        }
    }
}

// ---------------------------------------------------------------------------
// Step-0 propagation straight from fp32 F0: computes own and neighbor
// cosine-norms on the fly (shared shuffle-reduce), so no separate
// normalize/pack kernel is needed. Writes packed bf16 Fu + nrm for step 1.
// ---------------------------------------------------------------------------
__global__ __launch_bounds__(256, 4) void propagate_f0(
    const float* __restrict__ F0,
    const int* __restrict__ ell, const int* __restrict__ deg,
    const float* __restrict__ invD, const float* __restrict__ invDsq,
    const float* __restrict__ raw_gamma,
    unsigned* __restrict__ Pout, float* __restrict__ nrmOut)
{
    int lane = threadIdx.x & 63;
    int wid  = threadIdx.x >> 6;
    int r    = __builtin_amdgcn_readfirstlane(blockIdx.x * 4 + wid);
    int g    = lane >> 3;
    int sl   = lane & 7;
    const float inv_am1 = 1.0f / (SCAD_A - 1.0f);

    float gamma = 2.0f / (1.0f + expf(-raw_gamma[0]));
    float lam_k = fmaxf(gamma / SCAD_A, 1e-8f);
    float tt    = SCAD_A * lam_k;

    int dg = deg[r];
    int pad = (dg + 15) & ~15;
    int npair = pad >> 4;
    const int* nb = ell + (size_t)r * MAX_DEG;
    int ed0 = (lane < pad)      ? nb[lane]      : r;
    int ed1 = (64 + lane < pad) ? nb[64 + lane] : r;

    float iDs = invDsq[r];
    const float4* f04 = (const float4*)(F0 + (size_t)r * OUT_DIM + sl * 8);
    float4 fa = f04[0], fb = f04[1];
    float f0v[8] = { fa.x, fa.y, fa.z, fa.w, fb.x, fb.y, fb.z, fb.w };
    float ui[8];
    float ssr = 0.0f;
#pragma unroll
    for (int q = 0; q < 8; q++) { ui[q] = f0v[q] * iDs; ssr += ui[q] * ui[q]; }
    ssr += __shfl_xor(ssr, 1, 64);
    ssr += __shfl_xor(ssr, 2, 64);
    ssr += __shfl_xor(ssr, 4, 64);
    float inv_nr = 1.0f / fmaxf(sqrtf(ssr), 1e-12f);
#pragma unroll
    for (int q = 0; q < 8; q++) ui[q] *= inv_nr;

    float acc[8] = {};
    float qsum = 0.0f;
    for (int it = 0; it < npair; ++it) {
        int e0 = it * 16 + g, e1 = e0 + 8;
        int src = (it < 4) ? ed0 : ed1;
        int j0 = __shfl(src, e0 & 63, 64);
        int j1 = __shfl(src, e1 & 63, 64);
        const float4* p0 = (const float4*)(F0 + (size_t)j0 * OUT_DIM + sl * 8);
        const float4* p1 = (const float4*)(F0 + (size_t)j1 * OUT_DIM + sl * 8);
        float4 x0 = p0[0], x1 = p0[1];
        float4 y0 = p1[0], y1 = p1[1];
        float d0 = invDsq[j0], d1 = invDsq[j1];
        float v0[8] = { x0.x*d0, x0.y*d0, x0.z*d0, x0.w*d0, x1.x*d0, x1.y*d0, x1.z*d0, x1.w*d0 };
        float v1[8] = { y0.x*d1, y0.y*d1, y0.z*d1, y0.w*d1, y1.x*d1, y1.y*d1, y1.z*d1, y1.w*d1 };
        float pa = 0.f, pb = 0.f, s0 = 0.f, s1 = 0.f;
#pragma unroll
        for (int q = 0; q < 8; q++) {
            pa += ui[q] * v0[q]; s0 += v0[q] * v0[q];
            pb += ui[q] * v1[q]; s1 += v1[q] * v1[q];
        }
        pa += __shfl_xor(pa, 1, 64); pb += __shfl_xor(pb, 1, 64);
        s0 += __shfl_xor(s0, 1, 64); s1 += __shfl_xor(s1, 1, 64);
        pa += __shfl_xor(pa, 2, 64); pb += __shfl_xor(pb, 2, 64);
        s0 += __shfl_xor(s0, 2, 64); s1 += __shfl_xor(s1, 2, 64);
        pa += __shfl_xor(pa, 4, 64); pb += __shfl_xor(pb, 4, 64);
        s0 += __shfl_xor(s0, 4, 64); s1 += __shfl_xor(s1, 4, 64);
        float n0 = fmaxf(sqrtf(s0), 1e-12f);
        float n1 = fmaxf(sqrtf(s1), 1e-12f);
        float ya = 1.0f - pa / n0, yb = 1.0f - pb / n1;
        float wa = (ya <= lam_k) ? 1.0f : ((ya <= tt) ? (tt - ya) * inv_am1 / ya : 0.0f);
        float wb = (yb <= lam_k) ? 1.0f : ((yb <= tt) ? (tt - yb) * inv_am1 / yb : 0.0f);
        if (e0 >= dg) wa = 0.0f;
        if (e1 >= dg) wb = 0.0f;
        qsum += wa + wb;
#pragma unroll
        for (int q = 0; q < 8; q++) acc[q] += wa * v0[q] + wb * v1[q];
    }

#pragma unroll
    for (int off = 8; off <= 32; off <<= 1) {
#pragma unroll
        for (int q = 0; q < 8; q++) acc[q] += __shfl_xor(acc[q], off, 64);
        qsum += __shfl_xor(qsum, off, 64);
    }

    float Qh  = qsum * invD[r] + LAM_CONST;
    float rQh = 1.0f / Qh;
    float res[8], fn[8];
    float ssq = 0.0f;
#pragma unroll
    for (int q = 0; q < 8; q++) {
        res[q] = (acc[q] * iDs + LAM_CONST * f0v[q]) * rQh;
        fn[q]  = res[q] * iDs;
        ssq   += fn[q] * fn[q];
    }
    ssq += __shfl_xor(ssq, 1, 64);
    ssq += __shfl_xor(ssq, 2, 64);
    ssq += __shfl_xor(ssq, 4, 64);
    float nrm = fmaxf(sqrtf(ssq), 1e-12f);
    float inv_n = 1.0f / nrm;
    if (lane < 8) {
        uint4 fuPk;
        fuPk.x = pack2(fn[0] * inv_n, fn[1] * inv_n);
        fuPk.y = pack2(fn[2] * inv_n, fn[3] * inv_n);
        fuPk.z = pack2(fn[4] * inv_n, fn[5] * inv_n);
        fuPk.w = pack2(fn[6] * inv_n, fn[7] * inv_n);
        *(uint4*)(Pout + (size_t)r * 32 + sl * 4) = fuPk;
    }
    if (lane == 0) nrmOut[r] = nrm;
}

// ---------------------------------------------------------------------------
// Steps 1..9: packed bf16 gather path, now with a 2-deep register
// double-buffer (named A/B, no runtime-indexed arrays) so the next edge
// pair's L2 gathers are in flight under the current pair's ~100 VALU ops.
// ---------------------------------------------------------------------------
__global__ __launch_bounds__(256, 4) void propagate(
    const unsigned* __restrict__ Pin, const float* __restrict__ nrmIn,
    const float* __restrict__ F0,
    const int* __restrict__ ell, const int* __restrict__ deg,
    const float* __restrict__ invD, const float* __restrict__ invDsq,
    const float* __restrict__ raw_gamma, int step,
    unsigned* __restrict__ Pout, float* __restrict__ nrmOut,
    float* __restrict__ FcOut, int writeNext, int writeOut)
{
    int lane = threadIdx.x & 63;
    int wid  = threadIdx.x >> 6;
    int r    = __builtin_amdgcn_readfirstlane(blockIdx.x * 4 + wid);
    int g    = lane >> 3;              // edge group 0..7
    int sl   = lane & 7;               // feature slice
    const float inv_am1 = 1.0f / (SCAD_A - 1.0f);

    float gamma = 2.0f / (1.0f + expf(-raw_gamma[step]));
    float lam_k = fmaxf(gamma / SCAD_A, 1e-8f);
    float tt    = SCAD_A * lam_k;

    int dg = deg[r];
    int pad = (dg + 15) & ~15;
    int npair = pad >> 4;
    const int* nb = ell + (size_t)r * MAX_DEG;
    int ed0 = (lane < pad)      ? nb[lane]      : r;
    int ed1 = (64 + lane < pad) ? nb[64 + lane] : r;

    uint4 up = *(const uint4*)(Pin + (size_t)r * 32 + sl * 4);
    float ui[8] = { bflo(up.x), bfhi(up.x), bflo(up.y), bfhi(up.y),
                    bflo(up.z), bfhi(up.z), bflo(up.w), bfhi(up.w) };

    float acc[8] = {};
    float qsum = 0.0f;

    auto eidx = [&](int it_, int& J0, int& J1) {
        int e0_ = it_ * 16 + g;
        int src = (it_ < 4) ? ed0 : ed1;
        J0 = __shfl(src, e0_ & 63, 64);
        J1 = __shfl(src, (e0_ + 8) & 63, 64);
    };
    auto body = [&](int it_, uint4 U0, uint4 U1, float NR0, float NR1) {
        float pa = ui[0] * bflo(U0.x) + ui[1] * bfhi(U0.x) + ui[2] * bflo(U0.y) + ui[3] * bfhi(U0.y)
                 + ui[4] * bflo(U0.z) + ui[5] * bfhi(U0.z) + ui[6] * bflo(U0.w) + ui[7] * bfhi(U0.w);
        float pb = ui[0] * bflo(U1.x) + ui[1] * bfhi(U1.x) + ui[2] * bflo(U1.y) + ui[3] * bfhi(U1.y)
                 + ui[4] * bflo(U1.z) + ui[5] * bfhi(U1.z) + ui[6] * bflo(U1.w) + ui[7] * bfhi(U1.w);
        pa += __shfl_xor(pa, 1, 64); pb += __shfl_xor(pb, 1, 64);
        pa += __shfl_xor(pa, 2, 64); pb += __shfl_xor(pb, 2, 64);
        pa += __shfl_xor(pa, 4, 64); pb += __shfl_xor(pb, 4, 64);
        float ya = 1.0f - pa, yb = 1.0f - pb;
        float wa = (ya <= lam_k) ? 1.0f : ((ya <= tt) ? (tt - ya) * inv_am1 / ya : 0.0f);
        float wb = (yb <= lam_k) ? 1.0f : ((yb <= tt) ? (tt - yb) * inv_am1 / yb : 0.0f);
        int e0_ = it_ * 16 + g;
        if (e0_ >= dg)     wa = 0.0f;
        if (e0_ + 8 >= dg) wb = 0.0f;
        qsum += wa + wb;                             // Q_hat uses unscaled w
        float wsa = wa * NR0;                        // Fn[j] = Fu[j]*nrm[j]
        float wsb = wb * NR1;
        acc[0] += wsa * bflo(U0.x) + wsb * bflo(U1.x);
        acc[1] += wsa * bfhi(U0.x) + wsb * bfhi(U1.x);
        acc[2] += wsa * bflo(U0.y) + wsb * bflo(U1.y);
        acc[3] += wsa * bfhi(U0.y) + wsb * bfhi(U1.y);
        acc[4] += wsa * bflo(U0.z) + wsb * bflo(U1.z);
        acc[5] += wsa * bfhi(U0.z) + wsb * bfhi(U1.z);
        acc[6] += wsa * bflo(U0.w) + wsb * bflo(U1.w);
        acc[7] += wsa * bfhi(U0.w) + wsb * bfhi(U1.w);
    };

    if (npair > 0) {
        uint4 uA0, uA1, uB0, uB1;
        float nA0, nA1, nB0, nB1;
        int j0, j1;
        eidx(0, j0, j1);
        uA0 = *(const uint4*)(Pin + (size_t)j0 * 32 + sl * 4);
        uA1 = *(const uint4*)(Pin + (size_t)j1 * 32 + sl * 4);
        nA0 = nrmIn[j0]; nA1 = nrmIn[j1];
        int it = 0;
        while (true) {
            if (it + 1 < npair) {
                eidx(it + 1, j0, j1);
                uB0 = *(const uint4*)(Pin + (size_t)j0 * 32 + sl * 4);
                uB1 = *(const uint4*)(Pin + (size_t)j1 * 32 + sl * 4);
                nB0 = nrmIn[j0]; nB1 = nrmIn[j1];
            }
            body(it, uA0, uA1, nA0, nA1);
            ++it; if (it >= npair) break;
            if (it + 1 < npair) {
                eidx(it + 1, j0, j1);
                uA0 = *(const uint4*)(Pin + (size_t)j0 * 32 + sl * 4);
                uA1 = *(const uint4*)(Pin + (size_t)j1 * 32 + sl * 4);
                nA0 = nrmIn[j0]; nA1 = nrmIn[j1];
            }
            body(it, uB0, uB1, nB0, nB1);
            ++it; if (it >= npair) break;
        }
    }

    // cross-group reduction: every lane ends with the full row sums
#pragma unroll
    for (int off = 8; off <= 32; off <<= 1) {
#pragma unroll
        for (int q = 0; q < 8; q++) acc[q] += __shfl_xor(acc[q], off, 64);
        qsum += __shfl_xor(qsum, off, 64);
    }

    float iDs = invDsq[r];
    float Qh  = qsum * invD[r] + LAM_CONST;
    float rQh = 1.0f / Qh;
    const float4* f04 = (const float4*)(F0 + (size_t)r * OUT_DIM + sl * 8);
    float4 f0a = f04[0], f0b = f04[1];
    float f0v[8] = { f0a.x, f0a.y, f0a.z, f0a.w, f0b.x, f0b.y, f0b.z, f0b.w };
    float res[8];
#pragma unroll
    for (int q = 0; q < 8; q++) res[q] = (acc[q] * iDs + LAM_CONST * f0v[q]) * rQh;

    if (writeOut && lane < 8) {
        float4* o4 = (float4*)(FcOut + (size_t)r * OUT_DIM + sl * 8);
        o4[0] = make_float4(res[0], res[1], res[2], res[3]);
        o4[1] = make_float4(res[4], res[5], res[6], res[7]);
    }
    if (writeNext) {
        float fn[8];
        float ssq = 0.0f;
#pragma unroll
        for (int q = 0; q < 8; q++) { fn[q] = res[q] * iDs; ssq += fn[q] * fn[q]; }
        ssq += __shfl_xor(ssq, 1, 64);   // lanes 0..7 mix among themselves
        ssq += __shfl_xor(ssq, 2, 64);
        ssq += __shfl_xor(ssq, 4, 64);
        float nrm = fmaxf(sqrtf(ssq), 1e-12f);
        float inv_n = 1.0f / nrm;
        if (lane < 8) {
            uint4 fuPk;
            fuPk.x = pack2(fn[0] * inv_n, fn[1] * inv_n);
            fuPk.y = pack2(fn[2] * inv_n, fn[3] * inv_n);
            fuPk.z = pack2(fn[4] * inv_n, fn[5] * inv_n);
            fuPk.w = pack2(fn[6] * inv_n, fn[7] * inv_n);
            *(uint4*)(Pout + (size_t)r * 32 + sl * 4) = fuPk;
        }
        if (lane == 0) nrmOut[r] = nrm;
    }
}

// ---------------------------------------------------------------------------
extern "C" void kernel_launch(void* const* d_in, const int* in_sizes, int n_in,
                              void* d_out, int out_size, void* d_ws, size_t ws_size,
                              hipStream_t stream)
{
    const float* A  = (const float*)d_in[0];
    const float* F  = (const float*)d_in[1];
    const float* W1 = (const float*)d_in[2];
    const float* b1 = (const float*)d_in[3];
    const float* W2 = (const float*)d_in[4];
    const float* b2 = (const float*)d_in[5];
    const float* rg = (const float*)d_in[6];
    float* out = (float*)d_out;

    // workspace layout (~4.6 MB)
    char* p = (char*)d_ws;
    float* F0     = (float*)p; p += (size_t)N_NODES * OUT_DIM * 4;           // 1 MB
    unsigned* Pa  = (unsigned*)p; p += (size_t)N_NODES * 32 * 4;             // 512 KB packed Fu
    unsigned* Pb  = (unsigned*)p; p += (size_t)N_NODES * 32 * 4;             // 512 KB
    float* nrmA   = (float*)p; p += (size_t)N_NODES * 4;                     // 16 KB
    float* nrmB   = (float*)p; p += (size_t)N_NODES * 4;
    float* invD   = (float*)p; p += (size_t)N_NODES * 4;
    float* invDsq = (float*)p; p += (size_t)N_NODES * 4;
    int*   deg    = (int*)p;   p += (size_t)N_NODES * 4;
    int*   ell    = (int*)p;   p += (size_t)N_NODES * MAX_DEG * 4;           // 2 MB

    build_all<<<GEMM_BLOCKS + N_NODES, 512, 0, stream>>>(
        A, F, W1, b1, W2, b2, F0, ell, deg, invD, invDsq);

    // step 0 straight from fp32 F0 (writes Pa/nrmA)
    propagate_f0<<<N_NODES / 4, 256, 0, stream>>>(
        F0, ell, deg, invD, invDsq, rg, Pa, nrmA);

    for (int k = 1; k < PROP_STEP; k++) {
        unsigned* Pin   = (k & 1) ? Pa : Pb;
        unsigned* Pout  = (k & 1) ? Pb : Pa;
        float* nIn      = (k & 1) ? nrmA : nrmB;
        float* nOut     = (k & 1) ? nrmB : nrmA;
        int last = (k == PROP_STEP - 1);
        propagate<<<N_NODES / 4, 256, 0, stream>>>(
            Pin, nIn, F0, ell, deg, invD, invDsq, rg, k,
            Pout, nOut, out, !last, last);
    }
}